// Round 11
// baseline (156.882 us; speedup 1.0000x reference)
//
#include <hip/hip_runtime.h>

typedef __attribute__((ext_vector_type(4))) float f32x4;
typedef __attribute__((ext_vector_type(8))) short short8;
typedef unsigned short ushort_t;
typedef unsigned int uint_t;

#define R_  32768
#define L_  6
#define EPS_ 1e-5f

// fragment-ordered weights in workspace:
//  w1s [L][2 half][4 wave][6 ft][6 kc][512]   (A-frags 16f x 32k)
//  w2s [L][2 half][4 wave][3 ei][12 kc2][512] (A-frags 16e x 32f)
//  wfr [6 vt][6 kc][512]                      (A-frags 16v x 32k)
#define NW_ 884736

__device__ __forceinline__ ushort_t f2bf(float f) {
    uint_t i = __builtin_bit_cast(uint_t, f);
    uint_t r = (i + 0x7fffu + ((i >> 16) & 1u)) >> 16;   // RNE
    return (ushort_t)r;
}
__device__ __forceinline__ uint_t cvtpk(float a, float b) {
    uint_t r;
    asm("v_cvt_pk_bf16_f32 %0, %1, %2" : "=v"(r) : "v"(a), "v"(b));
    return r;
}

// raw barrier: order LDS (lgkm) only — global loads stay in flight across it.
// sched_barrier fences both sides against compiler reordering (rule 18).
__device__ __forceinline__ void barx() {
    __builtin_amdgcn_sched_barrier(0);
    asm volatile("s_waitcnt lgkmcnt(0)" ::: "memory");
    __builtin_amdgcn_s_barrier();
    __builtin_amdgcn_sched_barrier(0);
}

// ---------------- weight convert: per-wave-slice fragment-ordered ----------------
__global__ void wconv_k(const float* __restrict__ W1, const float* __restrict__ W2,
                        const float* __restrict__ Wf,
                        ushort_t* __restrict__ w1s, ushort_t* __restrict__ w2s,
                        ushort_t* __restrict__ wfr)
{
    int i = blockIdx.x * 256 + threadIdx.x;
    if (i < NW_) {    // w1 frags: global frag q = (((l*2+half)*4+wv)*6+ft)*6+kc
        int j = i & 7, li = (i >> 3) & 63, q = i >> 9;
        int kc = q % 6; q /= 6;
        int ft = q % 6; q /= 6;
        int wv = q & 3; q >>= 2;
        int half = q & 1; int l = q >> 1;
        int f = half * 384 + wv * 96 + ft * 16 + (li & 15);
        int k = kc * 32 + ((li >> 4) << 3) + j;
        w1s[i] = f2bf(W1[((size_t)l * 192 + k) * 768 + f]);
        return;
    }
    i -= NW_;
    if (i < NW_) {    // w2 frags: q = (((l*2+half)*4+wv)*3+ei)*12+kc2
        int j = i & 7, li = (i >> 3) & 63, q = i >> 9;
        int kc2 = q % 12; q /= 12;
        int ei = q % 3; q /= 3;
        int wv = q & 3; q >>= 2;
        int half = q & 1; int l = q >> 1;
        int e = (wv + 4 * ei) * 16 + (li & 15);
        int k = half * 384 + kc2 * 32 + ((li >> 4) << 3) + j;
        w2s[i] = f2bf(W2[((size_t)l * 768 + k) * 192 + e]);
        return;
    }
    i -= NW_;
    if (i < 36 * 512) {   // head frags: q = vt*6+kc
        int j = i & 7, li = (i >> 3) & 63, q = i >> 9;
        int kc = q % 6, vt = q / 6;
        int v = vt * 16 + (li & 15);
        int k = kc * 32 + ((li >> 4) << 3) + j;
        wfr[i] = f2bf(Wf[(size_t)k * 96 + v]);
    }
}

// ---------------- whole network: block-cooperative, 64 rows/block ----------------
__global__ __launch_bounds__(256, 2) void net_k(
    const int* __restrict__ idxp, const int* __restrict__ tgp,
    const float* __restrict__ tok, const float* __restrict__ pos,
    const float* __restrict__ ln1g, const float* __restrict__ ln1b,
    const float* __restrict__ ln2g, const float* __restrict__ ln2b,
    const float* __restrict__ b1g, const float* __restrict__ b2g,
    const float* __restrict__ fng, const float* __restrict__ fnb,
    const float* __restrict__ bfb,
    const ushort_t* __restrict__ w1s, const ushort_t* __restrict__ w2s,
    const ushort_t* __restrict__ wfr,
    float* __restrict__ pred, float* __restrict__ partial)
{
    __shared__ __align__(16) ushort_t xb[6 * 4 * 512];     // x B-frags  [kc][rg][512] 24KB
    __shared__ __align__(16) ushort_t hbl[12 * 4 * 512];   // h B-frags  [kc2][rg][512] 48KB
    __shared__ __align__(16) float lnS1[64][4], lnQ1[64][4];
    __shared__ __align__(16) float lnS2[64][4], lnQ2[64][4];
    __shared__ float lsred[4];

    const int tid = threadIdx.x, lane = tid & 63, w = tid >> 6;
    const int c = lane & 15, g = lane >> 4;
    const int row0 = blockIdx.x * 64;

    // x state distributed: wave w owns e-tiles {w, w+4, w+8}; D-layout
    f32x4 xac[3][4];

    // ---- embedding (no barrier needed: no LDS touched yet) ----
#pragma unroll
    for (int rg = 0; rg < 4; ++rg) {
        int row = row0 + rg * 16 + c;
        int id = idxp[row];
        int tt = row & 127;
#pragma unroll
        for (int i = 0; i < 3; ++i) {
            int e0 = (w + 4 * i) * 16 + g * 4;
            float4 a = *(const float4*)(tok + (size_t)id * 192 + e0);
            float4 b = *(const float4*)(pos + (size_t)tt * 192 + e0);
            xac[i][rg][0] = a.x + b.x; xac[i][rg][1] = a.y + b.y;
            xac[i][rg][2] = a.z + b.z; xac[i][rg][3] = a.w + b.w;
        }
    }

#pragma unroll 1
    for (int l = 0; l < L_; ++l) {
        // ---- LN1 stats (cross-wave via LDS) ----
#pragma unroll
        for (int rg = 0; rg < 4; ++rg) {
            float s = 0.f, sq = 0.f;
#pragma unroll
            for (int i = 0; i < 3; ++i)
#pragma unroll
                for (int r = 0; r < 4; ++r) { float v = xac[i][rg][r]; s += v; sq += v * v; }
            s += __shfl_xor(s, 16); sq += __shfl_xor(sq, 16);
            s += __shfl_xor(s, 32); sq += __shfl_xor(sq, 32);
            if (g == 0) { lnS1[rg * 16 + c][w] = s; lnQ1[rg * 16 + c][w] = sq; }
        }
        barx();
        // ---- apply LN1, compute LN2 stats ----
#pragma unroll
        for (int rg = 0; rg < 4; ++rg) {
            float4 S = *(const float4*)lnS1[rg * 16 + c];
            float4 Q = *(const float4*)lnQ1[rg * 16 + c];
            float mu = (S.x + S.y + S.z + S.w) * (1.f / 192.f);
            float var = (Q.x + Q.y + Q.z + Q.w) * (1.f / 192.f) - mu * mu;
            float ri = rsqrtf(var + EPS_);
            float s2 = 0.f, q2 = 0.f;
#pragma unroll
            for (int i = 0; i < 3; ++i) {
                int e0 = (w + 4 * i) * 16 + g * 4;
                float4 gg = *(const float4*)(ln1g + l * 192 + e0);
                float4 bb = *(const float4*)(ln1b + l * 192 + e0);
                float n0 = (xac[i][rg][0] - mu) * ri * gg.x + bb.x;
                float n1 = (xac[i][rg][1] - mu) * ri * gg.y + bb.y;
                float n2 = (xac[i][rg][2] - mu) * ri * gg.z + bb.z;
                float n3 = (xac[i][rg][3] - mu) * ri * gg.w + bb.w;
                xac[i][rg][0] = n0; xac[i][rg][1] = n1; xac[i][rg][2] = n2; xac[i][rg][3] = n3;
                s2 += n0 + n1 + n2 + n3;
                q2 += n0 * n0 + n1 * n1 + n2 * n2 + n3 * n3;
            }
            s2 += __shfl_xor(s2, 16); q2 += __shfl_xor(q2, 16);
            s2 += __shfl_xor(s2, 32); q2 += __shfl_xor(q2, 32);
            if (g == 0) { lnS2[rg * 16 + c][w] = s2; lnQ2[rg * 16 + c][w] = q2; }
        }
        barx();
        // ---- apply LN2, pack n2 -> xb B-frags, zero accumulator ----
#pragma unroll
        for (int rg = 0; rg < 4; ++rg) {
            float4 S = *(const float4*)lnS2[rg * 16 + c];
            float4 Q = *(const float4*)lnQ2[rg * 16 + c];
            float mu = (S.x + S.y + S.z + S.w) * (1.f / 192.f);
            float var = (Q.x + Q.y + Q.z + Q.w) * (1.f / 192.f) - mu * mu;
            float ri = rsqrtf(var + EPS_);
#pragma unroll
            for (int i = 0; i < 3; ++i) {
                int et = w + 4 * i;
                int e0 = et * 16 + g * 4;
                float4 gg = *(const float4*)(ln2g + l * 192 + e0);
                float4 bb = *(const float4*)(ln2b + l * 192 + e0);
                float y0 = (xac[i][rg][0] - mu) * ri * gg.x + bb.x;
                float y1 = (xac[i][rg][1] - mu) * ri * gg.y + bb.y;
                float y2 = (xac[i][rg][2] - mu) * ri * gg.z + bb.z;
                float y3 = (xac[i][rg][3] - mu) * ri * gg.w + bb.w;
                uint_t d0 = cvtpk(y0, y1), d1 = cvtpk(y2, y3);
                int kc = et >> 1, floc = ((et & 1) << 4) + g * 4;
                int us = (kc * 4 + rg) * 512 + ((floc >> 3) * 16 + c) * 8 + (floc & 7);
                *(uint2*)(xb + us) = make_uint2(d0, d1);
                xac[i][rg][0] = 0.f; xac[i][rg][1] = 0.f; xac[i][rg][2] = 0.f; xac[i][rg][3] = 0.f;
            }
        }
        barx();

        // ---- FFN: two f-halves of 384 ----
#pragma unroll 1
        for (int half = 0; half < 2; ++half) {
            // prefetch gemm2 kh0 / ei{0,1} weight frags NOW — latency hides under
            // gemm1 and the loads survive the lgkm-only barrier (T4+T14)
            const ushort_t* w2p = w2s + ((size_t)((l * 2 + half) * 4 + w) * 36) * 512 + lane * 8;
            short8 wpre[12];
#pragma unroll
            for (int q = 0; q < 6; ++q) wpre[q] = *(const short8*)(w2p + q * 512);
#pragma unroll
            for (int q = 0; q < 6; ++q) wpre[6 + q] = *(const short8*)(w2p + (12 + q) * 512);

            // gemm1: wave's 96-f slice, weights global->reg, x from LDS
            const ushort_t* w1p = w1s + ((size_t)((l * 2 + half) * 4 + w) * 36) * 512 + lane * 8;
#pragma unroll
            for (int fth = 0; fth < 2; ++fth) {
                short8 wa[18];
#pragma unroll
                for (int q = 0; q < 18; ++q) wa[q] = *(const short8*)(w1p + (fth * 18 + q) * 512);
                float4 bbv[3];
#pragma unroll
                for (int f3 = 0; f3 < 3; ++f3)
                    bbv[f3] = *(const float4*)(b1g + l * 768 + half * 384 + w * 96 + (fth * 3 + f3) * 16 + g * 4);
#pragma unroll
                for (int rg = 0; rg < 4; ++rg) {
                    short8 xbf[6];
#pragma unroll
                    for (int kc = 0; kc < 6; ++kc)
                        xbf[kc] = *(const short8*)(xb + (kc * 4 + rg) * 512 + lane * 8);
#pragma unroll
                    for (int f3 = 0; f3 < 3; ++f3) {
                        f32x4 acc = {};
                        __builtin_amdgcn_s_setprio(1);
#pragma unroll
                        for (int kc = 0; kc < 6; ++kc)
                            acc = __builtin_amdgcn_mfma_f32_16x16x32_bf16(wa[f3 * 6 + kc], xbf[kc], acc, 0, 0, 0);
                        __builtin_amdgcn_s_setprio(0);
                        float y0 = fmaxf(acc[0] + bbv[f3].x, 0.f);
                        float y1 = fmaxf(acc[1] + bbv[f3].y, 0.f);
                        float y2 = fmaxf(acc[2] + bbv[f3].z, 0.f);
                        float y3 = fmaxf(acc[3] + bbv[f3].w, 0.f);
                        uint_t d0 = cvtpk(y0, y1), d1 = cvtpk(y2, y3);
                        int ft = fth * 3 + f3;
                        int kc2 = w * 3 + (ft >> 1);
                        int floc = ((ft & 1) << 4) + g * 4;
                        int us = (kc2 * 4 + rg) * 512 + ((floc >> 3) * 16 + c) * 8 + (floc & 7);
                        *(uint2*)(hbl + us) = make_uint2(d0, d1);
                    }
                }
            }
            barx();

            // gemm2: wave's 48-e slice; kh0/ei{0,1} use prefetched frags
#pragma unroll
            for (int kh = 0; kh < 2; ++kh) {
                short8 wr[18];
                if (kh == 0) {
#pragma unroll
                    for (int q = 0; q < 12; ++q) wr[q] = wpre[q];
#pragma unroll
                    for (int k6 = 0; k6 < 6; ++k6)
                        wr[12 + k6] = *(const short8*)(w2p + (24 + k6) * 512);
                } else {
#pragma unroll
                    for (int ei = 0; ei < 3; ++ei)
#pragma unroll
                        for (int k6 = 0; k6 < 6; ++k6)
                            wr[ei * 6 + k6] = *(const short8*)(w2p + (ei * 12 + 6 + k6) * 512);
                }
#pragma unroll
                for (int rg = 0; rg < 4; ++rg) {
                    short8 hbf[6];
#pragma unroll
                    for (int k6 = 0; k6 < 6; ++k6)
                        hbf[k6] = *(const short8*)(hbl + ((kh * 6 + k6) * 4 + rg) * 512 + lane * 8);
                    __builtin_amdgcn_s_setprio(1);
#pragma unroll
                    for (int ei = 0; ei < 3; ++ei)
#pragma unroll
                        for (int k6 = 0; k6 < 6; ++k6)
                            xac[ei][rg] = __builtin_amdgcn_mfma_f32_16x16x32_bf16(wr[ei * 6 + k6], hbf[k6], xac[ei][rg], 0, 0, 0);
                    __builtin_amdgcn_s_setprio(0);
                }
            }
            // barrier only between halves (hbl WAR); end-of-layer barrier is
            // redundant — next write to hbl/xb/lnS1 is >=3 barriers away
            if (half == 0) barx();
        }

        // ---- + bias2 ----
#pragma unroll
        for (int i = 0; i < 3; ++i) {
            int e0 = (w + 4 * i) * 16 + g * 4;
            float4 bb = *(const float4*)(b2g + l * 192 + e0);
#pragma unroll
            for (int rg = 0; rg < 4; ++rg) {
                xac[i][rg][0] += bb.x; xac[i][rg][1] += bb.y;
                xac[i][rg][2] += bb.z; xac[i][rg][3] += bb.w;
            }
        }
    }

    // ---- final LN ----
#pragma unroll
    for (int rg = 0; rg < 4; ++rg) {
        float s = 0.f, sq = 0.f;
#pragma unroll
        for (int i = 0; i < 3; ++i)
#pragma unroll
            for (int r = 0; r < 4; ++r) { float v = xac[i][rg][r]; s += v; sq += v * v; }
        s += __shfl_xor(s, 16); sq += __shfl_xor(sq, 16);
        s += __shfl_xor(s, 32); sq += __shfl_xor(sq, 32);
        if (g == 0) { lnS1[rg * 16 + c][w] = s; lnQ1[rg * 16 + c][w] = sq; }
    }
    barx();
#pragma unroll
    for (int rg = 0; rg < 4; ++rg) {
        float4 S = *(const float4*)lnS1[rg * 16 + c];
        float4 Q = *(const float4*)lnQ1[rg * 16 + c];
        float mu = (S.x + S.y + S.z + S.w) * (1.f / 192.f);
        float var = (Q.x + Q.y + Q.z + Q.w) * (1.f / 192.f) - mu * mu;
        float ri = rsqrtf(var + EPS_);
#pragma unroll
        for (int i = 0; i < 3; ++i) {
            int et = w + 4 * i;
            int e0 = et * 16 + g * 4;
            float4 gg = *(const float4*)(fng + e0);
            float4 bb = *(const float4*)(fnb + e0);
            float y0 = (xac[i][rg][0] - mu) * ri * gg.x + bb.x;
            float y1 = (xac[i][rg][1] - mu) * ri * gg.y + bb.y;
            float y2 = (xac[i][rg][2] - mu) * ri * gg.z + bb.z;
            float y3 = (xac[i][rg][3] - mu) * ri * gg.w + bb.w;
            uint_t d0 = cvtpk(y0, y1), d1 = cvtpk(y2, y3);
            int kc = et >> 1, floc = ((et & 1) << 4) + g * 4;
            int us = (kc * 4 + rg) * 512 + ((floc >> 3) * 16 + c) * 8 + (floc & 7);
            *(uint2*)(xb + us) = make_uint2(d0, d1);
        }
    }
    barx();

    // ---- head: wave w handles rows rg=w (16 rows), all 96 vocab ----
    short8 wfh[36];
    {
        const ushort_t* wfp = wfr + lane * 8;
#pragma unroll
        for (int q = 0; q < 36; ++q) wfh[q] = *(const short8*)(wfp + q * 512);
    }
    short8 xbf[6];
#pragma unroll
    for (int kc = 0; kc < 6; ++kc)
        xbf[kc] = *(const short8*)(xb + (kc * 4 + w) * 512 + lane * 8);
    f32x4 av[6] = {};
    __builtin_amdgcn_s_setprio(1);
#pragma unroll
    for (int vt = 0; vt < 6; ++vt)
#pragma unroll
        for (int kc = 0; kc < 6; ++kc)
            av[vt] = __builtin_amdgcn_mfma_f32_16x16x32_bf16(wfh[vt * 6 + kc], xbf[kc], av[vt], 0, 0, 0);
    __builtin_amdgcn_s_setprio(0);

    float vv[6][4];
#pragma unroll
    for (int vt = 0; vt < 6; ++vt) {
        float4 bb = *(const float4*)(bfb + vt * 16 + g * 4);
        vv[vt][0] = av[vt][0] + bb.x;
        vv[vt][1] = av[vt][1] + bb.y;
        vv[vt][2] = av[vt][2] + bb.z;
        vv[vt][3] = av[vt][3] + bb.w;
    }
    float mx = -1e30f;
#pragma unroll
    for (int vt = 0; vt < 6; ++vt)
#pragma unroll
        for (int r = 0; r < 4; ++r) mx = fmaxf(mx, vv[vt][r]);
    mx = fmaxf(mx, __shfl_xor(mx, 16));
    mx = fmaxf(mx, __shfl_xor(mx, 32));
    float se = 0.f;
#pragma unroll
    for (int vt = 0; vt < 6; ++vt)
#pragma unroll
        for (int r = 0; r < 4; ++r) se += expf(vv[vt][r] - mx);
    se += __shfl_xor(se, 16);
    se += __shfl_xor(se, 32);
    float lse = logf(se) + mx;
    int myrow = row0 + w * 16 + c;
    int tgt = tgp[myrow];
    float lsum = 0.f;
#pragma unroll
    for (int vt = 0; vt < 6; ++vt)
#pragma unroll
        for (int r = 0; r < 4; ++r)
            if (tgt == vt * 16 + g * 4 + r) lsum += lse - vv[vt][r];
#pragma unroll
    for (int vt = 0; vt < 6; ++vt) {
        float4 o;
        o.x = vv[vt][0]; o.y = vv[vt][1]; o.z = vv[vt][2]; o.w = vv[vt][3];
        *(float4*)(pred + (size_t)myrow * 96 + vt * 16 + g * 4) = o;
    }
#pragma unroll
    for (int m = 1; m < 64; m <<= 1) lsum += __shfl_xor(lsum, m);
    if (lane == 0) lsred[w] = lsum;
    barx();
    if (tid == 0) partial[blockIdx.x] = lsred[0] + lsred[1] + lsred[2] + lsred[3];
}

__global__ void lossred_k(const float* __restrict__ partial, float* __restrict__ out)
{
    __shared__ double sd[256];
    int t = threadIdx.x;
    sd[t] = (double)partial[t] + (double)partial[t + 256];
    __syncthreads();
    for (int s = 128; s > 0; s >>= 1) {
        if (t < s) sd[t] += sd[t + s];
        __syncthreads();
    }
    if (t == 0) out[0] = (float)(sd[0] / (double)R_);
}

extern "C" void kernel_launch(void* const* d_in, const int* in_sizes, int n_in,
                              void* d_out, int out_size, void* d_ws, size_t ws_size,
                              hipStream_t stream)
{
    (void)in_sizes; (void)n_in; (void)out_size; (void)ws_size;
    const int*   index   = (const int*)  d_in[0];
    const int*   targets = (const int*)  d_in[1];
    const float* tok     = (const float*)d_in[2];
    const float* pos     = (const float*)d_in[3];
    const float* ln1g    = (const float*)d_in[4];
    const float* ln1b    = (const float*)d_in[5];
    const float* ln2g    = (const float*)d_in[6];
    const float* ln2b    = (const float*)d_in[7];
    // d_in[8..10] = Wq/Wk/Wv: dead in the reference forward
    const float* W1      = (const float*)d_in[11];
    const float* b1      = (const float*)d_in[12];
    const float* W2      = (const float*)d_in[13];
    const float* b2      = (const float*)d_in[14];
    const float* fng     = (const float*)d_in[15];
    const float* fnb     = (const float*)d_in[16];
    const float* Wf      = (const float*)d_in[17];
    const float* bfv     = (const float*)d_in[18];

    ushort_t* w1s = (ushort_t*)d_ws;                        // [884736]
    ushort_t* w2s = w1s + NW_;                              // [884736]
    ushort_t* wfr = w2s + NW_;                              // [18432]
    float* partial = (float*)(wfr + 36 * 512);              // [512]
    float* pred  = (float*)d_out;
    float* lossp = pred + (size_t)R_ * 96;

    const int nconv = 2 * NW_ + 36 * 512;                   // 1787904 = 6984*256
    wconv_k<<<nconv / 256, 256, 0, stream>>>(W1, W2, Wf, w1s, w2s, wfr);
    net_k<<<512, 256, 0, stream>>>(index, targets, tok, pos, ln1g, ln1b, ln2g, ln2b,
                                   b1, b2, fng, fnb, bfv, w1s, w2s, wfr, pred, partial);
    lossred_k<<<1, 256, 0, stream>>>(partial, lossp);
}

// Round 12
// 148.615 us; speedup vs baseline: 1.0556x; 1.0556x over previous
//
#include <hip/hip_runtime.h>

typedef __attribute__((ext_vector_type(4))) float f32x4;
typedef __attribute__((ext_vector_type(8))) short short8;
typedef unsigned short ushort_t;
typedef unsigned int uint_t;

#define R_  32768
#define L_  6
#define EPS_ 1e-5f

// fragment-ordered weights in workspace:
//  w1s [L][2 half][4 wave][6 ft][6 kc][512]   (A-frags 16f x 32k)
//  w2s [L][2 half][4 wave][3 ei][12 kc2][512] (A-frags 16e x 32f)
//  wfr [6 vt][6 kc][512]                      (A-frags 16v x 32k)
#define NW_ 884736

__device__ __forceinline__ ushort_t f2bf(float f) {
    uint_t i = __builtin_bit_cast(uint_t, f);
    uint_t r = (i + 0x7fffu + ((i >> 16) & 1u)) >> 16;   // RNE
    return (ushort_t)r;
}
__device__ __forceinline__ uint_t cvtpk(float a, float b) {
    uint_t r;
    asm("v_cvt_pk_bf16_f32 %0, %1, %2" : "=v"(r) : "v"(a), "v"(b));
    return r;
}

// ---------------- weight convert: per-wave-slice fragment-ordered ----------------
__global__ void wconv_k(const float* __restrict__ W1, const float* __restrict__ W2,
                        const float* __restrict__ Wf,
                        ushort_t* __restrict__ w1s, ushort_t* __restrict__ w2s,
                        ushort_t* __restrict__ wfr)
{
    int i = blockIdx.x * 256 + threadIdx.x;
    if (i < NW_) {    // w1 frags: global frag q = (((l*2+half)*4+wv)*6+ft)*6+kc
        int j = i & 7, li = (i >> 3) & 63, q = i >> 9;
        int kc = q % 6; q /= 6;
        int ft = q % 6; q /= 6;
        int wv = q & 3; q >>= 2;
        int half = q & 1; int l = q >> 1;
        int f = half * 384 + wv * 96 + ft * 16 + (li & 15);
        int k = kc * 32 + ((li >> 4) << 3) + j;
        w1s[i] = f2bf(W1[((size_t)l * 192 + k) * 768 + f]);
        return;
    }
    i -= NW_;
    if (i < NW_) {    // w2 frags: q = (((l*2+half)*4+wv)*3+ei)*12+kc2
        int j = i & 7, li = (i >> 3) & 63, q = i >> 9;
        int kc2 = q % 12; q /= 12;
        int ei = q % 3; q /= 3;
        int wv = q & 3; q >>= 2;
        int half = q & 1; int l = q >> 1;
        int e = (wv + 4 * ei) * 16 + (li & 15);
        int k = half * 384 + kc2 * 32 + ((li >> 4) << 3) + j;
        w2s[i] = f2bf(W2[((size_t)l * 768 + k) * 192 + e]);
        return;
    }
    i -= NW_;
    if (i < 36 * 512) {   // head frags: q = vt*6+kc
        int j = i & 7, li = (i >> 3) & 63, q = i >> 9;
        int kc = q % 6, vt = q / 6;
        int v = vt * 16 + (li & 15);
        int k = kc * 32 + ((li >> 4) << 3) + j;
        wfr[i] = f2bf(Wf[(size_t)k * 96 + v]);
    }
}

// ---------------- whole network: block-cooperative, 64 rows/block ----------------
__global__ __launch_bounds__(256, 2) void net_k(
    const int* __restrict__ idxp, const int* __restrict__ tgp,
    const float* __restrict__ tok, const float* __restrict__ pos,
    const float* __restrict__ ln1g, const float* __restrict__ ln1b,
    const float* __restrict__ ln2g, const float* __restrict__ ln2b,
    const float* __restrict__ b1g, const float* __restrict__ b2g,
    const float* __restrict__ fng, const float* __restrict__ fnb,
    const float* __restrict__ bfb,
    const ushort_t* __restrict__ w1s, const ushort_t* __restrict__ w2s,
    const ushort_t* __restrict__ wfr,
    float* __restrict__ pred, float* __restrict__ partial)
{
    __shared__ __align__(16) ushort_t xb[6 * 4 * 512];     // x B-frags  [kc][rg][512] 24KB
    __shared__ __align__(16) ushort_t hbl[12 * 4 * 512];   // h B-frags  [kc2][rg][512] 48KB
    __shared__ __align__(16) float lnS1[64][4], lnQ1[64][4];
    __shared__ __align__(16) float lnS2[64][4], lnQ2[64][4];
    __shared__ float lsred[4];

    const int tid = threadIdx.x, lane = tid & 63, w = tid >> 6;
    const int c = lane & 15, g = lane >> 4;
    const int row0 = blockIdx.x * 64;

    // x state distributed: wave w owns e-tiles {w, w+4, w+8}; D-layout
    f32x4 xac[3][4];

    // ---- embedding (no LDS touched yet -> no barrier) ----
#pragma unroll
    for (int rg = 0; rg < 4; ++rg) {
        int row = row0 + rg * 16 + c;
        int id = idxp[row];
        int tt = row & 127;
#pragma unroll
        for (int i = 0; i < 3; ++i) {
            int e0 = (w + 4 * i) * 16 + g * 4;
            float4 a = *(const float4*)(tok + (size_t)id * 192 + e0);
            float4 b = *(const float4*)(pos + (size_t)tt * 192 + e0);
            xac[i][rg][0] = a.x + b.x; xac[i][rg][1] = a.y + b.y;
            xac[i][rg][2] = a.z + b.z; xac[i][rg][3] = a.w + b.w;
        }
    }

#pragma unroll 1
    for (int l = 0; l < L_; ++l) {
        // ---- LN1 stats (cross-wave via LDS) ----
#pragma unroll
        for (int rg = 0; rg < 4; ++rg) {
            float s = 0.f, sq = 0.f;
#pragma unroll
            for (int i = 0; i < 3; ++i)
#pragma unroll
                for (int r = 0; r < 4; ++r) { float v = xac[i][rg][r]; s += v; sq += v * v; }
            s += __shfl_xor(s, 16); sq += __shfl_xor(sq, 16);
            s += __shfl_xor(s, 32); sq += __shfl_xor(sq, 32);
            if (g == 0) { lnS1[rg * 16 + c][w] = s; lnQ1[rg * 16 + c][w] = sq; }
        }
        __syncthreads();
        // ---- apply LN1, compute LN2 stats ----
#pragma unroll
        for (int rg = 0; rg < 4; ++rg) {
            float4 S = *(const float4*)lnS1[rg * 16 + c];
            float4 Q = *(const float4*)lnQ1[rg * 16 + c];
            float mu = (S.x + S.y + S.z + S.w) * (1.f / 192.f);
            float var = (Q.x + Q.y + Q.z + Q.w) * (1.f / 192.f) - mu * mu;
            float ri = rsqrtf(var + EPS_);
            float s2 = 0.f, q2 = 0.f;
#pragma unroll
            for (int i = 0; i < 3; ++i) {
                int e0 = (w + 4 * i) * 16 + g * 4;
                float4 gg = *(const float4*)(ln1g + l * 192 + e0);
                float4 bb = *(const float4*)(ln1b + l * 192 + e0);
                float n0 = (xac[i][rg][0] - mu) * ri * gg.x + bb.x;
                float n1 = (xac[i][rg][1] - mu) * ri * gg.y + bb.y;
                float n2 = (xac[i][rg][2] - mu) * ri * gg.z + bb.z;
                float n3 = (xac[i][rg][3] - mu) * ri * gg.w + bb.w;
                xac[i][rg][0] = n0; xac[i][rg][1] = n1; xac[i][rg][2] = n2; xac[i][rg][3] = n3;
                s2 += n0 + n1 + n2 + n3;
                q2 += n0 * n0 + n1 * n1 + n2 * n2 + n3 * n3;
            }
            s2 += __shfl_xor(s2, 16); q2 += __shfl_xor(q2, 16);
            s2 += __shfl_xor(s2, 32); q2 += __shfl_xor(q2, 32);
            if (g == 0) { lnS2[rg * 16 + c][w] = s2; lnQ2[rg * 16 + c][w] = q2; }
        }
        __syncthreads();
        // ---- apply LN2, pack n2 -> xb B-frags, init accumulator with b2 ----
#pragma unroll
        for (int rg = 0; rg < 4; ++rg) {
            float4 S = *(const float4*)lnS2[rg * 16 + c];
            float4 Q = *(const float4*)lnQ2[rg * 16 + c];
            float mu = (S.x + S.y + S.z + S.w) * (1.f / 192.f);
            float var = (Q.x + Q.y + Q.z + Q.w) * (1.f / 192.f) - mu * mu;
            float ri = rsqrtf(var + EPS_);
#pragma unroll
            for (int i = 0; i < 3; ++i) {
                int et = w + 4 * i;
                int e0 = et * 16 + g * 4;
                float4 gg = *(const float4*)(ln2g + l * 192 + e0);
                float4 bb = *(const float4*)(ln2b + l * 192 + e0);
                float y0 = (xac[i][rg][0] - mu) * ri * gg.x + bb.x;
                float y1 = (xac[i][rg][1] - mu) * ri * gg.y + bb.y;
                float y2 = (xac[i][rg][2] - mu) * ri * gg.z + bb.z;
                float y3 = (xac[i][rg][3] - mu) * ri * gg.w + bb.w;
                uint_t d0 = cvtpk(y0, y1), d1 = cvtpk(y2, y3);
                int kc = et >> 1, floc = ((et & 1) << 4) + g * 4;
                int us = (kc * 4 + rg) * 512 + ((floc >> 3) * 16 + c) * 8 + (floc & 7);
                *(uint2*)(xb + us) = make_uint2(d0, d1);
                // init accumulator with bias2 (replaces end-of-layer bias add)
                float4 b2v = *(const float4*)(b2g + l * 192 + e0);
                xac[i][rg][0] = b2v.x; xac[i][rg][1] = b2v.y;
                xac[i][rg][2] = b2v.z; xac[i][rg][3] = b2v.w;
            }
        }
        __syncthreads();

        // ---- FFN: two f-halves of 384 ----
#pragma unroll 1
        for (int half = 0; half < 2; ++half) {
            // gemm1: wave's 96-f slice, weights global->reg, x from LDS
            const ushort_t* w1p = w1s + ((size_t)((l * 2 + half) * 4 + w) * 36) * 512 + lane * 8;
#pragma unroll
            for (int fth = 0; fth < 2; ++fth) {
                short8 wa[18];
#pragma unroll
                for (int q = 0; q < 18; ++q) wa[q] = *(const short8*)(w1p + (fth * 18 + q) * 512);
                float4 bbv[3];
#pragma unroll
                for (int f3 = 0; f3 < 3; ++f3)
                    bbv[f3] = *(const float4*)(b1g + l * 768 + half * 384 + w * 96 + (fth * 3 + f3) * 16 + g * 4);
#pragma unroll
                for (int rg = 0; rg < 4; ++rg) {
                    short8 xbf[6];
#pragma unroll
                    for (int kc = 0; kc < 6; ++kc)
                        xbf[kc] = *(const short8*)(xb + (kc * 4 + rg) * 512 + lane * 8);
#pragma unroll
                    for (int f3 = 0; f3 < 3; ++f3) {
                        // bias preloaded into the accumulator (C-in of MFMA)
                        f32x4 acc;
                        acc[0] = bbv[f3].x; acc[1] = bbv[f3].y;
                        acc[2] = bbv[f3].z; acc[3] = bbv[f3].w;
                        __builtin_amdgcn_s_setprio(1);
#pragma unroll
                        for (int kc = 0; kc < 6; ++kc)
                            acc = __builtin_amdgcn_mfma_f32_16x16x32_bf16(wa[f3 * 6 + kc], xbf[kc], acc, 0, 0, 0);
                        __builtin_amdgcn_s_setprio(0);
                        float y0 = fmaxf(acc[0], 0.f);
                        float y1 = fmaxf(acc[1], 0.f);
                        float y2 = fmaxf(acc[2], 0.f);
                        float y3 = fmaxf(acc[3], 0.f);
                        uint_t d0 = cvtpk(y0, y1), d1 = cvtpk(y2, y3);
                        int ft = fth * 3 + f3;
                        int kc2 = w * 3 + (ft >> 1);
                        int floc = ((ft & 1) << 4) + g * 4;
                        int us = (kc2 * 4 + rg) * 512 + ((floc >> 3) * 16 + c) * 8 + (floc & 7);
                        *(uint2*)(hbl + us) = make_uint2(d0, d1);
                    }
                }
            }
            __syncthreads();

            // gemm2: wave's 48-e slice, weights global->reg, h from LDS
            const ushort_t* w2p = w2s + ((size_t)((l * 2 + half) * 4 + w) * 36) * 512 + lane * 8;
#pragma unroll
            for (int kh = 0; kh < 2; ++kh) {
                short8 wr[18];
#pragma unroll
                for (int ei = 0; ei < 3; ++ei)
#pragma unroll
                    for (int k6 = 0; k6 < 6; ++k6)
                        wr[ei * 6 + k6] = *(const short8*)(w2p + (ei * 12 + kh * 6 + k6) * 512);
#pragma unroll
                for (int rg = 0; rg < 4; ++rg) {
                    short8 hbf[6];
#pragma unroll
                    for (int k6 = 0; k6 < 6; ++k6)
                        hbf[k6] = *(const short8*)(hbl + ((kh * 6 + k6) * 4 + rg) * 512 + lane * 8);
                    __builtin_amdgcn_s_setprio(1);
#pragma unroll
                    for (int ei = 0; ei < 3; ++ei)
#pragma unroll
                        for (int k6 = 0; k6 < 6; ++k6)
                            xac[ei][rg] = __builtin_amdgcn_mfma_f32_16x16x32_bf16(wr[ei * 6 + k6], hbf[k6], xac[ei][rg], 0, 0, 0);
                    __builtin_amdgcn_s_setprio(0);
                }
            }
            // barrier only between halves (hbl WAR); end-of-layer barrier is
            // redundant — next hbl write is >=3 barriers away (LN phases)
            if (half == 0) __syncthreads();
        }
        // (bias2 already in accumulator via init)
    }

    // ---- final LN (single) ----
#pragma unroll
    for (int rg = 0; rg < 4; ++rg) {
        float s = 0.f, sq = 0.f;
#pragma unroll
        for (int i = 0; i < 3; ++i)
#pragma unroll
            for (int r = 0; r < 4; ++r) { float v = xac[i][rg][r]; s += v; sq += v * v; }
        s += __shfl_xor(s, 16); sq += __shfl_xor(sq, 16);
        s += __shfl_xor(s, 32); sq += __shfl_xor(sq, 32);
        if (g == 0) { lnS1[rg * 16 + c][w] = s; lnQ1[rg * 16 + c][w] = sq; }
    }
    __syncthreads();
#pragma unroll
    for (int rg = 0; rg < 4; ++rg) {
        float4 S = *(const float4*)lnS1[rg * 16 + c];
        float4 Q = *(const float4*)lnQ1[rg * 16 + c];
        float mu = (S.x + S.y + S.z + S.w) * (1.f / 192.f);
        float var = (Q.x + Q.y + Q.z + Q.w) * (1.f / 192.f) - mu * mu;
        float ri = rsqrtf(var + EPS_);
#pragma unroll
        for (int i = 0; i < 3; ++i) {
            int et = w + 4 * i;
            int e0 = et * 16 + g * 4;
            float4 gg = *(const float4*)(fng + e0);
            float4 bb = *(const float4*)(fnb + e0);
            float y0 = (xac[i][rg][0] - mu) * ri * gg.x + bb.x;
            float y1 = (xac[i][rg][1] - mu) * ri * gg.y + bb.y;
            float y2 = (xac[i][rg][2] - mu) * ri * gg.z + bb.z;
            float y3 = (xac[i][rg][3] - mu) * ri * gg.w + bb.w;
            uint_t d0 = cvtpk(y0, y1), d1 = cvtpk(y2, y3);
            int kc = et >> 1, floc = ((et & 1) << 4) + g * 4;
            int us = (kc * 4 + rg) * 512 + ((floc >> 3) * 16 + c) * 8 + (floc & 7);
            *(uint2*)(xb + us) = make_uint2(d0, d1);
        }
    }
    __syncthreads();

    // ---- head: wave w handles rows rg=w (16 rows), all 96 vocab ----
    short8 wfh[36];
    {
        const ushort_t* wfp = wfr + lane * 8;
#pragma unroll
        for (int q = 0; q < 36; ++q) wfh[q] = *(const short8*)(wfp + q * 512);
    }
    short8 xbf[6];
#pragma unroll
    for (int kc = 0; kc < 6; ++kc)
        xbf[kc] = *(const short8*)(xb + (kc * 4 + w) * 512 + lane * 8);
    f32x4 av[6] = {};
    __builtin_amdgcn_s_setprio(1);
#pragma unroll
    for (int vt = 0; vt < 6; ++vt)
#pragma unroll
        for (int kc = 0; kc < 6; ++kc)
            av[vt] = __builtin_amdgcn_mfma_f32_16x16x32_bf16(wfh[vt * 6 + kc], xbf[kc], av[vt], 0, 0, 0);
    __builtin_amdgcn_s_setprio(0);

    float vv[6][4];
#pragma unroll
    for (int vt = 0; vt < 6; ++vt) {
        float4 bb = *(const float4*)(bfb + vt * 16 + g * 4);
        vv[vt][0] = av[vt][0] + bb.x;
        vv[vt][1] = av[vt][1] + bb.y;
        vv[vt][2] = av[vt][2] + bb.z;
        vv[vt][3] = av[vt][3] + bb.w;
    }
    float mx = -1e30f;
#pragma unroll
    for (int vt = 0; vt < 6; ++vt)
#pragma unroll
        for (int r = 0; r < 4; ++r) mx = fmaxf(mx, vv[vt][r]);
    mx = fmaxf(mx, __shfl_xor(mx, 16));
    mx = fmaxf(mx, __shfl_xor(mx, 32));
    float se = 0.f;
#pragma unroll
    for (int vt = 0; vt < 6; ++vt)
#pragma unroll
        for (int r = 0; r < 4; ++r) se += expf(vv[vt][r] - mx);
    se += __shfl_xor(se, 16);
    se += __shfl_xor(se, 32);
    float lse = logf(se) + mx;
    int myrow = row0 + w * 16 + c;
    int tgt = tgp[myrow];
    float lsum = 0.f;
#pragma unroll
    for (int vt = 0; vt < 6; ++vt)
#pragma unroll
        for (int r = 0; r < 4; ++r)
            if (tgt == vt * 16 + g * 4 + r) lsum += lse - vv[vt][r];
#pragma unroll
    for (int vt = 0; vt < 6; ++vt) {
        float4 o;
        o.x = vv[vt][0]; o.y = vv[vt][1]; o.z = vv[vt][2]; o.w = vv[vt][3];
        *(float4*)(pred + (size_t)myrow * 96 + vt * 16 + g * 4) = o;
    }
#pragma unroll
    for (int m = 1; m < 64; m <<= 1) lsum += __shfl_xor(lsum, m);
    if (lane == 0) lsred[w] = lsum;
    __syncthreads();
    if (tid == 0) partial[blockIdx.x] = lsred[0] + lsred[1] + lsred[2] + lsred[3];
}

__global__ void lossred_k(const float* __restrict__ partial, float* __restrict__ out)
{
    __shared__ double sd[256];
    int t = threadIdx.x;
    sd[t] = (double)partial[t] + (double)partial[t + 256];
    __syncthreads();
    for (int s = 128; s > 0; s >>= 1) {
        if (t < s) sd[t] += sd[t + s];
        __syncthreads();
    }
    if (t == 0) out[0] = (float)(sd[0] / (double)R_);
}

extern "C" void kernel_launch(void* const* d_in, const int* in_sizes, int n_in,
                              void* d_out, int out_size, void* d_ws, size_t ws_size,
                              hipStream_t stream)
{
    (void)in_sizes; (void)n_in; (void)out_size; (void)ws_size;
    const int*   index   = (const int*)  d_in[0];
    const int*   targets = (const int*)  d_in[1];
    const float* tok     = (const float*)d_in[2];
    const float* pos     = (const float*)d_in[3];
    const float* ln1g    = (const float*)d_in[4];
    const float* ln1b    = (const float*)d_in[5];
    const float* ln2g    = (const float*)d_in[6];
    const float* ln2b    = (const float*)d_in[7];
    // d_in[8..10] = Wq/Wk/Wv: dead in the reference forward
    const float* W1      = (const float*)d_in[11];
    const float* b1      = (const float*)d_in[12];
    const float* W2      = (const float*)d_in[13];
    const float* b2      = (const float*)d_in[14];
    const float* fng     = (const float*)d_in[15];
    const float* fnb     = (const float*)d_in[16];
    const float* Wf      = (const float*)d_in[17];
    const float* bfv     = (const float*)d_in[18];

    ushort_t* w1s = (ushort_t*)d_ws;                        // [884736]
    ushort_t* w2s = w1s + NW_;                              // [884736]
    ushort_t* wfr = w2s + NW_;                              // [18432]
    float* partial = (float*)(wfr + 36 * 512);              // [512]
    float* pred  = (float*)d_out;
    float* lossp = pred + (size_t)R_ * 96;

    const int nconv = 2 * NW_ + 36 * 512;                   // 1787904 = 6984*256
    wconv_k<<<nconv / 256, 256, 0, stream>>>(W1, W2, Wf, w1s, w2s, wfr);
    net_k<<<512, 256, 0, stream>>>(index, targets, tok, pos, ln1g, ln1b, ln2g, ln2b,
                                   b1, b2, fng, fnb, bfv, w1s, w2s, wfr, pred, partial);
    lossred_k<<<1, 256, 0, stream>>>(partial, lossp);
}